// Round 12
// baseline (843.131 us; speedup 1.0000x reference)
//
#include <hip/hip_runtime.h>
#include <math.h>

#pragma clang fp contract(off)

typedef float v2f __attribute__((ext_vector_type(2)));

// Exact-FMA helper: ONLY used with multiplier 0.125f (power of two).
// 0.125*q is exact (exponent shift, operands normal, in [0,1]), so
// fma(0.125,q,acc) == round(exact_product + acc) == separate mul-then-add,
// BIT-IDENTICAL. The c15=1/15 chains are NOT fused (mul rounds there).
__device__ __forceinline__ v2f fma2(v2f q, v2f c, v2f acc) {
    return __builtin_elementwise_fma(q, c, acc);
}

#define RR 7
#define HH 2048
#define WW 2048
#define PH 2062
#define PW 2062
#define PITCH 2080
#define PLANE (PITCH * PH)

#define BLK 64          // ONE wave per block (R9): waves fully autonomous
#define WVOUT 112       // output cols per wave (56 lanes x 2); 128 staged - 16 halo
#define TYB 32          // output rows per block (R3: 16 regressed; keep 32)
#define GX 19           // 19*112 = 2128 >= 2062
#define GY 65           // 65*32 = 2080 >= 2062

__global__ __launch_bounds__(256) void sw_pad(const float* __restrict__ img,
                                              float* __restrict__ dst) {
    int idx = blockIdx.x * blockDim.x + threadIdx.x;
    if (idx >= PW * PH) return;
    int y = idx / PW, x = idx - y * PW;
    int sy = y - RR; sy = sy < 0 ? 0 : (sy > HH - 1 ? HH - 1 : sy);
    int sx = x - RR; sx = sx < 0 ? 0 : (sx > WW - 1 ? WW - 1 : sx);
    const float* p = img + ((long)sy * WW + sx) * 3;
    long o = (long)y * PITCH + x;
    dst[o] = p[0];
    dst[(long)PLANE + o] = p[1];
    dst[2L * PLANE + o] = p[2];
}

__global__ __launch_bounds__(256) void sw_crop(const float* __restrict__ src,
                                               float* __restrict__ out) {
    int idx = blockIdx.x * blockDim.x + threadIdx.x;
    if (idx >= HH * WW) return;
    int y = idx / WW, x = idx - y * WW;
    long o = (long)(y + RR) * PITCH + (x + RR);
    out[(long)idx * 3 + 0] = src[o];
    out[(long)idx * 3 + 1] = src[(long)PLANE + o];
    out[(long)idx * 3 + 2] = src[2L * PLANE + o];
}

__global__ __launch_bounds__(BLK) void sw_iter(const float* __restrict__ src,
                                               float* __restrict__ dst) {
    // One autonomous wave: stages 128 cols (2/lane), outputs 112.
    // LDS 8 KB: [row s 0..3][even 64 | odd 64] float4.
    // No __syncthreads; lgkmcnt(0)+sched_barrier fence between write and
    // read phases (rule #18). 0.125-chains use exact FMA (see fma2 proof);
    // c15 chains stay mul+add (fusing them would change rounding -> R2 fail).
    __shared__ float4 lds4[4 * 128];
    const int l = threadIdx.x;                // lane 0..63
    const int xw0 = blockIdx.x * WVOUT;
    const int y0 = blockIdx.y * TYB;
    const int z = blockIdx.z;
    const float* sp = src + (long)z * PLANE;
    float* dp = dst + (long)z * PLANE;

    const int gc0 = xw0 - 8 + 2 * l;          // this lane's even staged col
    const bool gok = (gc0 >= 0) && (gc0 < PW);
    const int oc0 = xw0 + 2 * l;              // this lane's even output col
    const bool comp = (l < WVOUT / 2) && (oc0 < PW);

    const float c15 = 1.0f / 15.0f;
    const v2f c125v = {0.125f, 0.125f};

    // register ring: input rows (slot = row & 15), packed {even col, odd col}
    v2f xab[16];
#pragma unroll
    for (int i = 0; i < 16; ++i) { xab[i] = (v2f){0.0f, 0.0f}; }

    // warm-up: rows y0-7 .. y0+6
#pragma unroll
    for (int k = 0; k < 14; ++k) {
        const int r = y0 - 7 + k;
        v2f v = (v2f){0.0f, 0.0f};
        if (gok && r >= 0) v = *(const v2f*)(sp + (long)r * PITCH + gc0);
        xab[(k + 9) & 15] = v;
    }

    // prefetch chunk 0's input rows (y0+7 .. y0+10) into registers
    v2f pf[4];
#pragma unroll
    for (int s = 0; s < 4; ++s) {
        const int t = y0 + 7 + s;
        v2f v = (v2f){0.0f, 0.0f};
        if (gok && t < PH) v = *(const v2f*)(sp + (long)t * PITCH + gc0);
        pf[s] = v;
    }

    // outer loop ROLLED (I$: full unroll would be ~2x the 32 KB I$).
    // ring slot (16*cc + 4*c4 + s) & 15 == (4*c4 + s) & 15: cc-independent.
#pragma unroll 1
    for (int cc = 0; cc < 2; ++cc) {
        const int ybase = y0 + 16 * cc;
#pragma unroll
        for (int c4 = 0; c4 < 4; ++c4) {
            // ---- vertical stage: rows m = ybase+4*c4+s, inputs from pf[] ----
#pragma unroll
            for (int s = 0; s < 4; ++s) {
                const int jm = (4 * c4 + s) & 15;
                xab[(jm + 7) & 15] = pf[s];

                // aL/aR: 0.125 chains -> exact FMA (bit-identical, see proof)
                v2f aL = 0.125f * xab[(jm + 9) & 15];
#pragma unroll
                for (int k = 1; k < 8; ++k) {
                    aL = fma2(xab[(jm + 9 + k) & 15], c125v, aL);
                }
                v2f aR = 0.125f * xab[jm & 15];       // tap k=7 = row m
#pragma unroll
                for (int k = 8; k < 15; ++k) {
                    aR = fma2(xab[(jm + 9 + k) & 15], c125v, aR);
                }
                // aF: c15 chain -> mul+add unchanged (c15 mul rounds)
                v2f aF = c15 * xab[(jm + 9) & 15];
#pragma unroll
                for (int k = 1; k < 15; ++k) {
                    aF = aF + c15 * xab[(jm + 9 + k) & 15];
                }
                const v2f X = xab[jm & 15];
                lds4[s * 128 + l]      = make_float4(aL.x, aR.x, aF.x, X.x); // even
                lds4[s * 128 + 64 + l] = make_float4(aL.y, aR.y, aF.y, X.y); // odd
            }
            // wave-sync: ensure our ds_writes land before neighbor-lane reads.
            asm volatile("s_waitcnt lgkmcnt(0)" ::: "memory");
            __builtin_amdgcn_sched_barrier(0);

            // ---- prefetch next chunk's rows: horizontal phase hides latency ----
            if (4 * cc + c4 + 1 < 8) {
#pragma unroll
                for (int s = 0; s < 4; ++s) {
                    const int t = ybase + 4 * (c4 + 1) + 7 + s;
                    v2f v = (v2f){0.0f, 0.0f};
                    if (gok && t < PH) v = *(const v2f*)(sp + (long)t * PITCH + gc0);
                    pf[s] = v;
                }
            }

            // ---- horizontal stage (wave-private LDS reads) ----
            if (comp) {
#pragma unroll 2
                for (int s = 0; s < 4; ++s) {
                    const int m = ybase + 4 * c4 + s;
                    if (m >= PH) break;
                    const float4* rowb = lds4 + s * 128;
                    const float4* Eb = rowb + l + 1;      // even cols oc0-6+2k
                    const float4* Ob = rowb + 64 + l;     // odd cols  oc0-7+2k

                    // 16 taps j=0..15 ascending cols oc0-7..oc0+8.
                    // xy chains packed per pixel; z chains packed ACROSS pixels
                    // (lane0=p0, lane1=p1; p1 init via exact add-to-zero).
                    // 0.125 chains via exact FMA; c15 chains mul+add.
                    v2f a0L, a0R, f0, a1L, a1R, f1;
                    v2f zL, zR;
                    float xc0, xc1;
                    // j=0: q=Ob[0]; p0 i=0
                    {
                        float4 q = Ob[0];
                        v2f qxy = {q.x, q.y};
                        a0L = 0.125f * qxy;
                        f0 = c15 * qxy;
                        zL = (v2f){0.125f * q.z, 0.0f};
                    }
                    // j=1: q=Eb[0]; p0 i=1; p1 i=0 (init)
                    {
                        float4 q = Eb[0];
                        v2f qxy = {q.x, q.y};
                        a0L = fma2(qxy, c125v, a0L); f0 = f0 + c15 * qxy;
                        a1L = 0.125f * qxy;          f1 = c15 * qxy;
                        v2f qzz = {q.z, q.z};
                        zL = fma2(qzz, c125v, zL);   // lane1: 0 + t = t (exact init)
                    }
                    // j=2..6: both pixels aL+f; z chain
#pragma unroll
                    for (int j = 2; j <= 6; ++j) {
                        float4 q = (j & 1) ? Eb[(j - 1) >> 1] : Ob[j >> 1];
                        v2f qxy = {q.x, q.y};
                        a0L = fma2(qxy, c125v, a0L); f0 = f0 + c15 * qxy;
                        a1L = fma2(qxy, c125v, a1L); f1 = f1 + c15 * qxy;
                        v2f qzz = {q.z, q.z};
                        zL = fma2(qzz, c125v, zL);
                    }
                    // j=7: q=Eb[3]; p0 i=7 (aL add, aR init, xc0); p1 i=6
                    {
                        float4 q = Eb[3];
                        v2f qxy = {q.x, q.y};
                        a0L = fma2(qxy, c125v, a0L); f0 = f0 + c15 * qxy;
                        a0R = 0.125f * qxy;          xc0 = q.w;
                        a1L = fma2(qxy, c125v, a1L); f1 = f1 + c15 * qxy;
                        v2f qzz = {q.z, q.z};
                        zL = fma2(qzz, c125v, zL);
                        zR.x = 0.125f * q.z;      // p0 aRz init
                    }
                    // j=8: q=Ob[4]; p0 i=8 (aR add); p1 i=7 (aL add, aR init, xc1)
                    {
                        float4 q = Ob[4];
                        v2f qxy = {q.x, q.y};
                        a0R = fma2(qxy, c125v, a0R); f0 = f0 + c15 * qxy;
                        a1L = fma2(qxy, c125v, a1L); f1 = f1 + c15 * qxy;
                        a1R = 0.125f * qxy;          xc1 = q.w;
                        float t = 0.125f * q.z;   // exact product, reused 3x
                        zR.x = zR.x + t;          // p0 aRz add (i=8)
                        zL.y = zL.y + t;          // p1 aLz add (i=7)
                        zR.y = t;                 // p1 aRz init (i=7)
                    }
                    // j=9..14: both pixels aR+f; z chain
#pragma unroll
                    for (int j = 9; j <= 14; ++j) {
                        float4 q = (j & 1) ? Eb[(j - 1) >> 1] : Ob[j >> 1];
                        v2f qxy = {q.x, q.y};
                        a0R = fma2(qxy, c125v, a0R); f0 = f0 + c15 * qxy;
                        a1R = fma2(qxy, c125v, a1R); f1 = f1 + c15 * qxy;
                        v2f qzz = {q.z, q.z};
                        zR = fma2(qzz, c125v, zR);
                    }
                    // j=15: q=Eb[7]; p1 i=14 only
                    {
                        float4 q = Eb[7];
                        v2f qxy = {q.x, q.y};
                        a1R = fma2(qxy, c125v, a1R); f1 = f1 + c15 * qxy;
                        zR.y = fmaf(0.125f, q.z, zR.y);   // exact (pow2 mul)
                    }

                    // argmin: d-values via packed subs (lane-wise identical to
                    // scalar); candidate ORDER identical to verified baseline.
                    v2f xcz = {xc0, xc1};
                    v2f dzL = zL - xcz, dzR = zR - xcz;

                    v2f xc0p = {xc0, xc0};
                    v2f dL = a0L - xc0p, dR = a0R - xc0p, dF = f0 - xc0p;
                    float d0 = dL.x, d1 = dR.x, d2 = dL.y, d3 = dR.y;
                    float d4 = dF.x, d5 = dF.y, d6 = dzL.x, d7 = dzR.x;
                    float best = d0, ba = fabsf(d0), a;
                    a = fabsf(d1); if (a < ba) { ba = a; best = d1; }
                    a = fabsf(d2); if (a < ba) { ba = a; best = d2; }
                    a = fabsf(d3); if (a < ba) { ba = a; best = d3; }
                    a = fabsf(d4); if (a < ba) { ba = a; best = d4; }
                    a = fabsf(d5); if (a < ba) { ba = a; best = d5; }
                    a = fabsf(d6); if (a < ba) { ba = a; best = d6; }
                    a = fabsf(d7); if (a < ba) { ba = a; best = d7; }
                    float out0 = xc0 + best;

                    v2f xc1p = {xc1, xc1};
                    dL = a1L - xc1p; dR = a1R - xc1p; dF = f1 - xc1p;
                    d0 = dL.x; d1 = dR.x; d2 = dL.y; d3 = dR.y;
                    d4 = dF.x; d5 = dF.y; d6 = dzL.y; d7 = dzR.y;
                    best = d0; ba = fabsf(d0);
                    a = fabsf(d1); if (a < ba) { ba = a; best = d1; }
                    a = fabsf(d2); if (a < ba) { ba = a; best = d2; }
                    a = fabsf(d3); if (a < ba) { ba = a; best = d3; }
                    a = fabsf(d4); if (a < ba) { ba = a; best = d4; }
                    a = fabsf(d5); if (a < ba) { ba = a; best = d5; }
                    a = fabsf(d6); if (a < ba) { ba = a; best = d6; }
                    a = fabsf(d7); if (a < ba) { ba = a; best = d7; }
                    float out1 = xc1 + best;

                    *(float2*)(dp + (long)m * PITCH + oc0) = make_float2(out0, out1);
                }
            }
        }
    }
}

extern "C" void kernel_launch(void* const* d_in, const int* in_sizes, int n_in,
                              void* d_out, int out_size, void* d_ws, size_t ws_size,
                              hipStream_t stream) {
    (void)in_sizes; (void)n_in; (void)out_size; (void)ws_size;
    const float* img = (const float*)d_in[0];
    float* out = (float*)d_out;
    float* A = (float*)d_ws;
    float* B = A + 3L * PLANE;

    {
        int total = PW * PH;
        int g = (total + 255) / 256;
        sw_pad<<<dim3(g), dim3(256), 0, stream>>>(img, A);
    }
    dim3 grid(GX, GY, 3), block(BLK);
    for (int i = 0; i < 10; ++i) {
        const float* s = (i & 1) ? B : A;
        float* d = (i & 1) ? A : B;
        sw_iter<<<grid, block, 0, stream>>>(s, d);
    }
    // iter 9 (odd) writes A: final state in A.
    {
        int total = HH * WW;
        int g = (total + 255) / 256;
        sw_crop<<<dim3(g), dim3(256), 0, stream>>>(A, out);
    }
}

// Round 13
// 679.673 us; speedup vs baseline: 1.2405x; 1.2405x over previous
//
#include <hip/hip_runtime.h>
#include <math.h>

#pragma clang fp contract(off)

typedef float v2f __attribute__((ext_vector_type(2)));

// Exact-FMA helper: ONLY used with multiplier 0.125f (power of two).
// 0.125*q is exact (exponent shift, operands normal, in [0,1]), so
// fma(0.125,q,acc) == round(exact_product + acc) == separate mul-then-add,
// BIT-IDENTICAL. The c15=1/15 chains are NOT fused (mul rounds there).
__device__ __forceinline__ v2f fma2(v2f q, v2f c, v2f acc) {
    return __builtin_elementwise_fma(q, c, acc);
}

#define RR 7
#define HH 2048
#define WW 2048
#define PH 2062
#define PW 2062
#define PITCH 2080
#define PLANE (PITCH * PH)

#define BLK 64          // ONE wave per block (R9): waves fully autonomous
#define WVOUT 112       // output cols per wave (56 lanes x 2); 128 staged - 16 halo
#define TYB 16          // R13: halve rows/block to DOUBLE wave supply per CU
                        // (occupancy pinned at ~1.7 waves/SIMD was the stall;
                        // LDS 8KB caps residency at 20 blocks/CU = 5/SIMD)
#define GX 19           // 19*112 = 2128 >= 2062
#define GY 129          // 129*16 = 2064 >= 2062

__global__ __launch_bounds__(256) void sw_pad(const float* __restrict__ img,
                                              float* __restrict__ dst) {
    int idx = blockIdx.x * blockDim.x + threadIdx.x;
    if (idx >= PW * PH) return;
    int y = idx / PW, x = idx - y * PW;
    int sy = y - RR; sy = sy < 0 ? 0 : (sy > HH - 1 ? HH - 1 : sy);
    int sx = x - RR; sx = sx < 0 ? 0 : (sx > WW - 1 ? WW - 1 : sx);
    const float* p = img + ((long)sy * WW + sx) * 3;
    long o = (long)y * PITCH + x;
    dst[o] = p[0];
    dst[(long)PLANE + o] = p[1];
    dst[2L * PLANE + o] = p[2];
}

__global__ __launch_bounds__(256) void sw_crop(const float* __restrict__ src,
                                               float* __restrict__ out) {
    int idx = blockIdx.x * blockDim.x + threadIdx.x;
    if (idx >= HH * WW) return;
    int y = idx / WW, x = idx - y * WW;
    long o = (long)(y + RR) * PITCH + (x + RR);
    out[(long)idx * 3 + 0] = src[o];
    out[(long)idx * 3 + 1] = src[(long)PLANE + o];
    out[(long)idx * 3 + 2] = src[2L * PLANE + o];
}

__global__ __launch_bounds__(BLK) void sw_iter(const float* __restrict__ src,
                                               float* __restrict__ dst) {
    // One autonomous wave: stages 128 cols (2/lane), outputs 112 x 16 rows.
    // LDS 8 KB: [row s 0..3][even 64 | odd 64] float4.
    // No __syncthreads; lgkmcnt(0)+sched_barrier fence between write and
    // read phases (rule #18). 0.125-chains use exact FMA (fma2 proof);
    // c15 chains stay mul+add. 16 rows = one ring period -> 4 chunks fully
    // unrolled (~45 KB body; R6 showed even 90 KB was wall-neutral).
    __shared__ float4 lds4[4 * 128];
    const int l = threadIdx.x;                // lane 0..63
    const int xw0 = blockIdx.x * WVOUT;
    const int y0 = blockIdx.y * TYB;
    const int z = blockIdx.z;
    const float* sp = src + (long)z * PLANE;
    float* dp = dst + (long)z * PLANE;

    const int gc0 = xw0 - 8 + 2 * l;          // this lane's even staged col
    const bool gok = (gc0 >= 0) && (gc0 < PW);
    const int oc0 = xw0 + 2 * l;              // this lane's even output col
    const bool comp = (l < WVOUT / 2) && (oc0 < PW);

    const float c15 = 1.0f / 15.0f;
    const v2f c125v = {0.125f, 0.125f};

    // register ring: input rows (slot = (row - y0) & 15), packed {even, odd}
    v2f xab[16];
#pragma unroll
    for (int i = 0; i < 16; ++i) { xab[i] = (v2f){0.0f, 0.0f}; }

    // warm-up: rows y0-7 .. y0+6
#pragma unroll
    for (int k = 0; k < 14; ++k) {
        const int r = y0 - 7 + k;
        v2f v = (v2f){0.0f, 0.0f};
        if (gok && r >= 0) v = *(const v2f*)(sp + (long)r * PITCH + gc0);
        xab[(k + 9) & 15] = v;
    }

    // prefetch chunk 0's input rows (y0+7 .. y0+10) into registers
    v2f pf[4];
#pragma unroll
    for (int s = 0; s < 4; ++s) {
        const int t = y0 + 7 + s;
        v2f v = (v2f){0.0f, 0.0f};
        if (gok && t < PH) v = *(const v2f*)(sp + (long)t * PITCH + gc0);
        pf[s] = v;
    }

#pragma unroll
    for (int c4 = 0; c4 < 4; ++c4) {
        // ---- vertical stage: rows m = y0+4*c4+s, inputs from pf[] ----
#pragma unroll
        for (int s = 0; s < 4; ++s) {
            const int jm = (4 * c4 + s) & 15;
            xab[(jm + 7) & 15] = pf[s];

            // aL/aR: 0.125 chains -> exact FMA (bit-identical, see proof)
            v2f aL = 0.125f * xab[(jm + 9) & 15];
#pragma unroll
            for (int k = 1; k < 8; ++k) {
                aL = fma2(xab[(jm + 9 + k) & 15], c125v, aL);
            }
            v2f aR = 0.125f * xab[jm & 15];       // tap k=7 = row m
#pragma unroll
            for (int k = 8; k < 15; ++k) {
                aR = fma2(xab[(jm + 9 + k) & 15], c125v, aR);
            }
            // aF: c15 chain -> mul+add unchanged (c15 mul rounds)
            v2f aF = c15 * xab[(jm + 9) & 15];
#pragma unroll
            for (int k = 1; k < 15; ++k) {
                aF = aF + c15 * xab[(jm + 9 + k) & 15];
            }
            const v2f X = xab[jm & 15];
            lds4[s * 128 + l]      = make_float4(aL.x, aR.x, aF.x, X.x); // even
            lds4[s * 128 + 64 + l] = make_float4(aL.y, aR.y, aF.y, X.y); // odd
        }
        // wave-sync: ensure our ds_writes land before neighbor-lane reads.
        asm volatile("s_waitcnt lgkmcnt(0)" ::: "memory");
        __builtin_amdgcn_sched_barrier(0);

        // ---- prefetch next chunk's rows: horizontal phase hides latency ----
        if (c4 + 1 < 4) {
#pragma unroll
            for (int s = 0; s < 4; ++s) {
                const int t = y0 + 4 * (c4 + 1) + 7 + s;
                v2f v = (v2f){0.0f, 0.0f};
                if (gok && t < PH) v = *(const v2f*)(sp + (long)t * PITCH + gc0);
                pf[s] = v;
            }
        }

        // ---- horizontal stage (wave-private LDS reads) ----
        if (comp) {
#pragma unroll 2
            for (int s = 0; s < 4; ++s) {
                const int m = y0 + 4 * c4 + s;
                if (m >= PH) break;
                const float4* rowb = lds4 + s * 128;
                const float4* Eb = rowb + l + 1;      // even cols oc0-6+2k
                const float4* Ob = rowb + 64 + l;     // odd cols  oc0-7+2k

                // 16 taps j=0..15 ascending cols oc0-7..oc0+8.
                // xy chains packed per pixel; z chains packed ACROSS pixels
                // (lane0=p0, lane1=p1; p1 init via exact add-to-zero).
                // 0.125 chains via exact FMA; c15 chains mul+add.
                v2f a0L, a0R, f0, a1L, a1R, f1;
                v2f zL, zR;
                float xc0, xc1;
                // j=0: q=Ob[0]; p0 i=0
                {
                    float4 q = Ob[0];
                    v2f qxy = {q.x, q.y};
                    a0L = 0.125f * qxy;
                    f0 = c15 * qxy;
                    zL = (v2f){0.125f * q.z, 0.0f};
                }
                // j=1: q=Eb[0]; p0 i=1; p1 i=0 (init)
                {
                    float4 q = Eb[0];
                    v2f qxy = {q.x, q.y};
                    a0L = fma2(qxy, c125v, a0L); f0 = f0 + c15 * qxy;
                    a1L = 0.125f * qxy;          f1 = c15 * qxy;
                    v2f qzz = {q.z, q.z};
                    zL = fma2(qzz, c125v, zL);   // lane1: 0 + t = t (exact init)
                }
                // j=2..6: both pixels aL+f; z chain
#pragma unroll
                for (int j = 2; j <= 6; ++j) {
                    float4 q = (j & 1) ? Eb[(j - 1) >> 1] : Ob[j >> 1];
                    v2f qxy = {q.x, q.y};
                    a0L = fma2(qxy, c125v, a0L); f0 = f0 + c15 * qxy;
                    a1L = fma2(qxy, c125v, a1L); f1 = f1 + c15 * qxy;
                    v2f qzz = {q.z, q.z};
                    zL = fma2(qzz, c125v, zL);
                }
                // j=7: q=Eb[3]; p0 i=7 (aL add, aR init, xc0); p1 i=6
                {
                    float4 q = Eb[3];
                    v2f qxy = {q.x, q.y};
                    a0L = fma2(qxy, c125v, a0L); f0 = f0 + c15 * qxy;
                    a0R = 0.125f * qxy;          xc0 = q.w;
                    a1L = fma2(qxy, c125v, a1L); f1 = f1 + c15 * qxy;
                    v2f qzz = {q.z, q.z};
                    zL = fma2(qzz, c125v, zL);
                    zR.x = 0.125f * q.z;      // p0 aRz init
                }
                // j=8: q=Ob[4]; p0 i=8 (aR add); p1 i=7 (aL add, aR init, xc1)
                {
                    float4 q = Ob[4];
                    v2f qxy = {q.x, q.y};
                    a0R = fma2(qxy, c125v, a0R); f0 = f0 + c15 * qxy;
                    a1L = fma2(qxy, c125v, a1L); f1 = f1 + c15 * qxy;
                    a1R = 0.125f * qxy;          xc1 = q.w;
                    float t = 0.125f * q.z;   // exact product, reused 3x
                    zR.x = zR.x + t;          // p0 aRz add (i=8)
                    zL.y = zL.y + t;          // p1 aLz add (i=7)
                    zR.y = t;                 // p1 aRz init (i=7)
                }
                // j=9..14: both pixels aR+f; z chain
#pragma unroll
                for (int j = 9; j <= 14; ++j) {
                    float4 q = (j & 1) ? Eb[(j - 1) >> 1] : Ob[j >> 1];
                    v2f qxy = {q.x, q.y};
                    a0R = fma2(qxy, c125v, a0R); f0 = f0 + c15 * qxy;
                    a1R = fma2(qxy, c125v, a1R); f1 = f1 + c15 * qxy;
                    v2f qzz = {q.z, q.z};
                    zR = fma2(qzz, c125v, zR);
                }
                // j=15: q=Eb[7]; p1 i=14 only
                {
                    float4 q = Eb[7];
                    v2f qxy = {q.x, q.y};
                    a1R = fma2(qxy, c125v, a1R); f1 = f1 + c15 * qxy;
                    zR.y = fmaf(0.125f, q.z, zR.y);   // exact (pow2 mul)
                }

                // argmin: d-values via packed subs (lane-wise identical to
                // scalar); candidate ORDER identical to verified baseline.
                v2f xcz = {xc0, xc1};
                v2f dzL = zL - xcz, dzR = zR - xcz;

                v2f xc0p = {xc0, xc0};
                v2f dL = a0L - xc0p, dR = a0R - xc0p, dF = f0 - xc0p;
                float d0 = dL.x, d1 = dR.x, d2 = dL.y, d3 = dR.y;
                float d4 = dF.x, d5 = dF.y, d6 = dzL.x, d7 = dzR.x;
                float best = d0, ba = fabsf(d0), a;
                a = fabsf(d1); if (a < ba) { ba = a; best = d1; }
                a = fabsf(d2); if (a < ba) { ba = a; best = d2; }
                a = fabsf(d3); if (a < ba) { ba = a; best = d3; }
                a = fabsf(d4); if (a < ba) { ba = a; best = d4; }
                a = fabsf(d5); if (a < ba) { ba = a; best = d5; }
                a = fabsf(d6); if (a < ba) { ba = a; best = d6; }
                a = fabsf(d7); if (a < ba) { ba = a; best = d7; }
                float out0 = xc0 + best;

                v2f xc1p = {xc1, xc1};
                dL = a1L - xc1p; dR = a1R - xc1p; dF = f1 - xc1p;
                d0 = dL.x; d1 = dR.x; d2 = dL.y; d3 = dR.y;
                d4 = dF.x; d5 = dF.y; d6 = dzL.y; d7 = dzR.y;
                best = d0; ba = fabsf(d0);
                a = fabsf(d1); if (a < ba) { ba = a; best = d1; }
                a = fabsf(d2); if (a < ba) { ba = a; best = d2; }
                a = fabsf(d3); if (a < ba) { ba = a; best = d3; }
                a = fabsf(d4); if (a < ba) { ba = a; best = d4; }
                a = fabsf(d5); if (a < ba) { ba = a; best = d5; }
                a = fabsf(d6); if (a < ba) { ba = a; best = d6; }
                a = fabsf(d7); if (a < ba) { ba = a; best = d7; }
                float out1 = xc1 + best;

                *(float2*)(dp + (long)m * PITCH + oc0) = make_float2(out0, out1);
            }
        }
    }
}

extern "C" void kernel_launch(void* const* d_in, const int* in_sizes, int n_in,
                              void* d_out, int out_size, void* d_ws, size_t ws_size,
                              hipStream_t stream) {
    (void)in_sizes; (void)n_in; (void)out_size; (void)ws_size;
    const float* img = (const float*)d_in[0];
    float* out = (float*)d_out;
    float* A = (float*)d_ws;
    float* B = A + 3L * PLANE;

    {
        int total = PW * PH;
        int g = (total + 255) / 256;
        sw_pad<<<dim3(g), dim3(256), 0, stream>>>(img, A);
    }
    dim3 grid(GX, GY, 3), block(BLK);
    for (int i = 0; i < 10; ++i) {
        const float* s = (i & 1) ? B : A;
        float* d = (i & 1) ? A : B;
        sw_iter<<<grid, block, 0, stream>>>(s, d);
    }
    // iter 9 (odd) writes A: final state in A.
    {
        int total = HH * WW;
        int g = (total + 255) / 256;
        sw_crop<<<dim3(g), dim3(256), 0, stream>>>(A, out);
    }
}

// Round 15
// 642.564 us; speedup vs baseline: 1.3121x; 1.0578x over previous
//
#include <hip/hip_runtime.h>
#include <math.h>

#pragma clang fp contract(off)

typedef float v2f __attribute__((ext_vector_type(2)));

// Exact-FMA helper: ONLY used with multiplier 0.125f (power of two).
// 0.125*q is exact (exponent shift, operands normal, in [0,1]), so
// fma(0.125,q,acc) == round(exact_product + acc) == separate mul-then-add,
// BIT-IDENTICAL. The c15=1/15 chains are NOT fused (mul rounds there).
__device__ __forceinline__ v2f fma2(v2f q, v2f c, v2f acc) {
    return __builtin_elementwise_fma(q, c, acc);
}

#define RR 7
#define HH 2048
#define WW 2048
#define PH 2062
#define PW 2062
#define PITCH 2080
#define PLANE (PITCH * PH)

#define BLK 64          // ONE wave per block (R9): waves fully autonomous
#define WVOUT 112       // output cols per wave (56 lanes x 2); 128 staged - 16 halo
#define TYB 8           // R14 retry: 2x wave supply vs R13. R14's fail was a
                        // warm-up guard bug (row >= PH read garbage), NOT the
                        // occupancy theory -- fixed below.
#define GX 19           // 19*112 = 2128 >= 2062
#define GY 258          // 258*8 = 2064 >= 2062

__global__ __launch_bounds__(256) void sw_pad(const float* __restrict__ img,
                                              float* __restrict__ dst) {
    int idx = blockIdx.x * blockDim.x + threadIdx.x;
    if (idx >= PW * PH) return;
    int y = idx / PW, x = idx - y * PW;
    int sy = y - RR; sy = sy < 0 ? 0 : (sy > HH - 1 ? HH - 1 : sy);
    int sx = x - RR; sx = sx < 0 ? 0 : (sx > WW - 1 ? WW - 1 : sx);
    const float* p = img + ((long)sy * WW + sx) * 3;
    long o = (long)y * PITCH + x;
    dst[o] = p[0];
    dst[(long)PLANE + o] = p[1];
    dst[2L * PLANE + o] = p[2];
}

__global__ __launch_bounds__(256) void sw_crop(const float* __restrict__ src,
                                               float* __restrict__ out) {
    int idx = blockIdx.x * blockDim.x + threadIdx.x;
    if (idx >= HH * WW) return;
    int y = idx / WW, x = idx - y * WW;
    long o = (long)(y + RR) * PITCH + (x + RR);
    out[(long)idx * 3 + 0] = src[o];
    out[(long)idx * 3 + 1] = src[(long)PLANE + o];
    out[(long)idx * 3 + 2] = src[2L * PLANE + o];
}

__global__ __launch_bounds__(BLK) void sw_iter(const float* __restrict__ src,
                                               float* __restrict__ dst) {
    // One autonomous wave: stages 128 cols (2/lane), outputs 112 x 8 rows.
    // LDS 8 KB: [row s 0..3][even 64 | odd 64] float4.
    // No __syncthreads; lgkmcnt(0)+sched_barrier fence between write and
    // read phases (rule #18). 0.125-chains use exact FMA (fma2 proof);
    // c15 chains stay mul+add.
    __shared__ float4 lds4[4 * 128];
    const int l = threadIdx.x;                // lane 0..63
    const int xw0 = blockIdx.x * WVOUT;
    const int y0 = blockIdx.y * TYB;
    const int z = blockIdx.z;
    const float* sp = src + (long)z * PLANE;
    float* dp = dst + (long)z * PLANE;

    const int gc0 = xw0 - 8 + 2 * l;          // this lane's even staged col
    const bool gok = (gc0 >= 0) && (gc0 < PW);
    const int oc0 = xw0 + 2 * l;              // this lane's even output col
    const bool comp = (l < WVOUT / 2) && (oc0 < PW);

    const float c15 = 1.0f / 15.0f;
    const v2f c125v = {0.125f, 0.125f};

    // register ring: input rows (slot = (row - y0) & 15), packed {even, odd}
    v2f xab[16];
#pragma unroll
    for (int i = 0; i < 16; ++i) { xab[i] = (v2f){0.0f, 0.0f}; }

    // warm-up: rows y0-7 .. y0+6.
    // GUARD r < PH (R14 bug): with TYB=8, bottom blocks' warm-up reaches row
    // 2062 >= PH; conv semantics require ZERO there, not an OOB read.
#pragma unroll
    for (int k = 0; k < 14; ++k) {
        const int r = y0 - 7 + k;
        v2f v = (v2f){0.0f, 0.0f};
        if (gok && r >= 0 && r < PH) v = *(const v2f*)(sp + (long)r * PITCH + gc0);
        xab[(k + 9) & 15] = v;
    }

    // prefetch chunk 0's input rows (y0+7 .. y0+10) into registers
    v2f pf[4];
#pragma unroll
    for (int s = 0; s < 4; ++s) {
        const int t = y0 + 7 + s;
        v2f v = (v2f){0.0f, 0.0f};
        if (gok && t < PH) v = *(const v2f*)(sp + (long)t * PITCH + gc0);
        pf[s] = v;
    }

#pragma unroll
    for (int c4 = 0; c4 < TYB / 4; ++c4) {
        // ---- vertical stage: rows m = y0+4*c4+s, inputs from pf[] ----
#pragma unroll
        for (int s = 0; s < 4; ++s) {
            const int jm = (4 * c4 + s) & 15;
            xab[(jm + 7) & 15] = pf[s];

            // aL/aR: 0.125 chains -> exact FMA (bit-identical, see proof)
            v2f aL = 0.125f * xab[(jm + 9) & 15];
#pragma unroll
            for (int k = 1; k < 8; ++k) {
                aL = fma2(xab[(jm + 9 + k) & 15], c125v, aL);
            }
            v2f aR = 0.125f * xab[jm & 15];       // tap k=7 = row m
#pragma unroll
            for (int k = 8; k < 15; ++k) {
                aR = fma2(xab[(jm + 9 + k) & 15], c125v, aR);
            }
            // aF: c15 chain -> mul+add unchanged (c15 mul rounds)
            v2f aF = c15 * xab[(jm + 9) & 15];
#pragma unroll
            for (int k = 1; k < 15; ++k) {
                aF = aF + c15 * xab[(jm + 9 + k) & 15];
            }
            const v2f X = xab[jm & 15];
            lds4[s * 128 + l]      = make_float4(aL.x, aR.x, aF.x, X.x); // even
            lds4[s * 128 + 64 + l] = make_float4(aL.y, aR.y, aF.y, X.y); // odd
        }
        // wave-sync: ensure our ds_writes land before neighbor-lane reads.
        asm volatile("s_waitcnt lgkmcnt(0)" ::: "memory");
        __builtin_amdgcn_sched_barrier(0);

        // ---- prefetch next chunk's rows: horizontal phase hides latency ----
        if (c4 + 1 < TYB / 4) {
#pragma unroll
            for (int s = 0; s < 4; ++s) {
                const int t = y0 + 4 * (c4 + 1) + 7 + s;
                v2f v = (v2f){0.0f, 0.0f};
                if (gok && t < PH) v = *(const v2f*)(sp + (long)t * PITCH + gc0);
                pf[s] = v;
            }
        }

        // ---- horizontal stage (wave-private LDS reads) ----
        if (comp) {
#pragma unroll 2
            for (int s = 0; s < 4; ++s) {
                const int m = y0 + 4 * c4 + s;
                if (m >= PH) break;
                const float4* rowb = lds4 + s * 128;
                const float4* Eb = rowb + l + 1;      // even cols oc0-6+2k
                const float4* Ob = rowb + 64 + l;     // odd cols  oc0-7+2k

                // 16 taps j=0..15 ascending cols oc0-7..oc0+8.
                // xy chains packed per pixel; z chains packed ACROSS pixels
                // (lane0=p0, lane1=p1; p1 init via exact add-to-zero).
                // 0.125 chains via exact FMA; c15 chains mul+add.
                v2f a0L, a0R, f0, a1L, a1R, f1;
                v2f zL, zR;
                float xc0, xc1;
                // j=0: q=Ob[0]; p0 i=0
                {
                    float4 q = Ob[0];
                    v2f qxy = {q.x, q.y};
                    a0L = 0.125f * qxy;
                    f0 = c15 * qxy;
                    zL = (v2f){0.125f * q.z, 0.0f};
                }
                // j=1: q=Eb[0]; p0 i=1; p1 i=0 (init)
                {
                    float4 q = Eb[0];
                    v2f qxy = {q.x, q.y};
                    a0L = fma2(qxy, c125v, a0L); f0 = f0 + c15 * qxy;
                    a1L = 0.125f * qxy;          f1 = c15 * qxy;
                    v2f qzz = {q.z, q.z};
                    zL = fma2(qzz, c125v, zL);   // lane1: 0 + t = t (exact init)
                }
                // j=2..6: both pixels aL+f; z chain
#pragma unroll
                for (int j = 2; j <= 6; ++j) {
                    float4 q = (j & 1) ? Eb[(j - 1) >> 1] : Ob[j >> 1];
                    v2f qxy = {q.x, q.y};
                    a0L = fma2(qxy, c125v, a0L); f0 = f0 + c15 * qxy;
                    a1L = fma2(qxy, c125v, a1L); f1 = f1 + c15 * qxy;
                    v2f qzz = {q.z, q.z};
                    zL = fma2(qzz, c125v, zL);
                }
                // j=7: q=Eb[3]; p0 i=7 (aL add, aR init, xc0); p1 i=6
                {
                    float4 q = Eb[3];
                    v2f qxy = {q.x, q.y};
                    a0L = fma2(qxy, c125v, a0L); f0 = f0 + c15 * qxy;
                    a0R = 0.125f * qxy;          xc0 = q.w;
                    a1L = fma2(qxy, c125v, a1L); f1 = f1 + c15 * qxy;
                    v2f qzz = {q.z, q.z};
                    zL = fma2(qzz, c125v, zL);
                    zR.x = 0.125f * q.z;      // p0 aRz init
                }
                // j=8: q=Ob[4]; p0 i=8 (aR add); p1 i=7 (aL add, aR init, xc1)
                {
                    float4 q = Ob[4];
                    v2f qxy = {q.x, q.y};
                    a0R = fma2(qxy, c125v, a0R); f0 = f0 + c15 * qxy;
                    a1L = fma2(qxy, c125v, a1L); f1 = f1 + c15 * qxy;
                    a1R = 0.125f * qxy;          xc1 = q.w;
                    float t = 0.125f * q.z;   // exact product, reused 3x
                    zR.x = zR.x + t;          // p0 aRz add (i=8)
                    zL.y = zL.y + t;          // p1 aLz add (i=7)
                    zR.y = t;                 // p1 aRz init (i=7)
                }
                // j=9..14: both pixels aR+f; z chain
#pragma unroll
                for (int j = 9; j <= 14; ++j) {
                    float4 q = (j & 1) ? Eb[(j - 1) >> 1] : Ob[j >> 1];
                    v2f qxy = {q.x, q.y};
                    a0R = fma2(qxy, c125v, a0R); f0 = f0 + c15 * qxy;
                    a1R = fma2(qxy, c125v, a1R); f1 = f1 + c15 * qxy;
                    v2f qzz = {q.z, q.z};
                    zR = fma2(qzz, c125v, zR);
                }
                // j=15: q=Eb[7]; p1 i=14 only
                {
                    float4 q = Eb[7];
                    v2f qxy = {q.x, q.y};
                    a1R = fma2(qxy, c125v, a1R); f1 = f1 + c15 * qxy;
                    zR.y = fmaf(0.125f, q.z, zR.y);   // exact (pow2 mul)
                }

                // argmin: d-values via packed subs (lane-wise identical to
                // scalar); candidate ORDER identical to verified baseline.
                v2f xcz = {xc0, xc1};
                v2f dzL = zL - xcz, dzR = zR - xcz;

                v2f xc0p = {xc0, xc0};
                v2f dL = a0L - xc0p, dR = a0R - xc0p, dF = f0 - xc0p;
                float d0 = dL.x, d1 = dR.x, d2 = dL.y, d3 = dR.y;
                float d4 = dF.x, d5 = dF.y, d6 = dzL.x, d7 = dzR.x;
                float best = d0, ba = fabsf(d0), a;
                a = fabsf(d1); if (a < ba) { ba = a; best = d1; }
                a = fabsf(d2); if (a < ba) { ba = a; best = d2; }
                a = fabsf(d3); if (a < ba) { ba = a; best = d3; }
                a = fabsf(d4); if (a < ba) { ba = a; best = d4; }
                a = fabsf(d5); if (a < ba) { ba = a; best = d5; }
                a = fabsf(d6); if (a < ba) { ba = a; best = d6; }
                a = fabsf(d7); if (a < ba) { ba = a; best = d7; }
                float out0 = xc0 + best;

                v2f xc1p = {xc1, xc1};
                dL = a1L - xc1p; dR = a1R - xc1p; dF = f1 - xc1p;
                d0 = dL.x; d1 = dR.x; d2 = dL.y; d3 = dR.y;
                d4 = dF.x; d5 = dF.y; d6 = dzL.y; d7 = dzR.y;
                best = d0; ba = fabsf(d0);
                a = fabsf(d1); if (a < ba) { ba = a; best = d1; }
                a = fabsf(d2); if (a < ba) { ba = a; best = d2; }
                a = fabsf(d3); if (a < ba) { ba = a; best = d3; }
                a = fabsf(d4); if (a < ba) { ba = a; best = d4; }
                a = fabsf(d5); if (a < ba) { ba = a; best = d5; }
                a = fabsf(d6); if (a < ba) { ba = a; best = d6; }
                a = fabsf(d7); if (a < ba) { ba = a; best = d7; }
                float out1 = xc1 + best;

                *(float2*)(dp + (long)m * PITCH + oc0) = make_float2(out0, out1);
            }
        }
    }
}

extern "C" void kernel_launch(void* const* d_in, const int* in_sizes, int n_in,
                              void* d_out, int out_size, void* d_ws, size_t ws_size,
                              hipStream_t stream) {
    (void)in_sizes; (void)n_in; (void)out_size; (void)ws_size;
    const float* img = (const float*)d_in[0];
    float* out = (float*)d_out;
    float* A = (float*)d_ws;
    float* B = A + 3L * PLANE;

    {
        int total = PW * PH;
        int g = (total + 255) / 256;
        sw_pad<<<dim3(g), dim3(256), 0, stream>>>(img, A);
    }
    dim3 grid(GX, GY, 3), block(BLK);
    for (int i = 0; i < 10; ++i) {
        const float* s = (i & 1) ? B : A;
        float* d = (i & 1) ? A : B;
        sw_iter<<<grid, block, 0, stream>>>(s, d);
    }
    // iter 9 (odd) writes A: final state in A.
    {
        int total = HH * WW;
        int g = (total + 255) / 256;
        sw_crop<<<dim3(g), dim3(256), 0, stream>>>(A, out);
    }
}